// Round 14
// baseline (360.100 us; speedup 1.0000x reference)
//
#include <hip/hip_runtime.h>
#include <hip/hip_bf16.h>
#include <hip/hip_fp16.h>

// Problem constants
#define BATCH 64
#define C_IN 16
#define T0 8192
#define T1 4096   // after pool1
#define T2 2048   // after pool2 (nodes per batch)
#define N_NODES (BATCH * T2)   // 131072
#define HID 64
#define NOUT 10

// Coarse-bucket edge partition parameters
#define NCB 256
#define CB_SHIFT 9
#define CB_TGT 512
#define RCAP 9216
#define PC_EDGES 2048
#define PC_CAP 28

// packed edge record: bits[0:17) = source r, bits[17:26) = local col
#define PK_RMASK 0x1FFFF

// per-block staged edge-span capacity
#define EC 1024

// zero-row index (tables have N_NODES+1 rows; row N_NODES is all zeros)
#define ZROW N_NODES

typedef __fp16 half8 __attribute__((ext_vector_type(8)));
typedef __fp16 half4v __attribute__((ext_vector_type(4)));
typedef float floatx4 __attribute__((ext_vector_type(4)));

// ---------------- conv1: [64,16,8192] -> relu -> pool2 -> h1 fp16 [64,16,4096]
__global__ __launch_bounds__(256) void conv1_kernel(const float* __restrict__ x,
    const float* __restrict__ w, const float* __restrict__ bias,
    __fp16* __restrict__ h1) {
  __shared__ float xs[16 * 520];
  int b = blockIdx.x >> 4;
  int tp0 = (blockIdx.x & 15) * 256;
  int t_base = tp0 * 2 - 2;
  const float* xb = x + (size_t)b * C_IN * T0;
  for (int idx = threadIdx.x; idx < 16 * 516; idx += 256) {
    int ci = idx / 516;
    int off = idx - ci * 516;
    int gt = t_base + off;
    float v = 0.f;
    if (gt >= 0 && gt < T0) v = xb[ci * T0 + gt];
    xs[ci * 520 + off] = v;
  }
  __syncthreads();
  int tp = threadIdx.x;
  float acc0[16], acc1[16];
#pragma unroll
  for (int co = 0; co < 16; ++co) { acc0[co] = 0.f; acc1[co] = 0.f; }
#pragma unroll 4
  for (int ci = 0; ci < 16; ++ci) {
    float xv[6];
#pragma unroll
    for (int k = 0; k < 6; ++k) xv[k] = xs[ci * 520 + 2 * tp + k];
#pragma unroll
    for (int co = 0; co < 16; ++co) {
#pragma unroll
      for (int k = 0; k < 5; ++k) {
        float wv = w[(co * 16 + ci) * 5 + k];
        acc0[co] += xv[k] * wv;
        acc1[co] += xv[k + 1] * wv;
      }
    }
  }
#pragma unroll
  for (int co = 0; co < 16; ++co) {
    float v = fmaxf(acc0[co], acc1[co]) + bias[co];
    v = fmaxf(v, 0.f);
    h1[((size_t)b * 16 + co) * T1 + tp0 + tp] = (__fp16)v;
  }
}

// ---------------- conv2 + gemm1 fused: h1 -> relu/pool -> (LDS) -> MFMA @W1
__global__ __launch_bounds__(256) void conv2_gemm1(const __fp16* __restrict__ h1,
    const float* __restrict__ w, const float* __restrict__ bias,
    const float* __restrict__ W1, const float* __restrict__ dis,
    __fp16* __restrict__ xw) {
  __shared__ float xs[16 * 520];
  __shared__ __fp16 fs[256 * 40];
  int b = blockIdx.x >> 3;
  int tp0 = (blockIdx.x & 7) * 256;
  int t_base = tp0 * 2 - 2;
  const __fp16* xb = h1 + (size_t)b * 16 * T1;
  for (int idx = threadIdx.x; idx < 16 * 516; idx += 256) {
    int ci = idx / 516;
    int off = idx - ci * 516;
    int gt = t_base + off;
    float v = 0.f;
    if (gt >= 0 && gt < T1) v = (float)xb[ci * T1 + gt];
    xs[ci * 520 + off] = v;
  }
  __syncthreads();
  int tp = threadIdx.x;
  float acc0[32], acc1[32];
#pragma unroll
  for (int co = 0; co < 32; ++co) { acc0[co] = 0.f; acc1[co] = 0.f; }
#pragma unroll 2
  for (int ci = 0; ci < 16; ++ci) {
    float xv[6];
#pragma unroll
    for (int k = 0; k < 6; ++k) xv[k] = xs[ci * 520 + 2 * tp + k];
#pragma unroll
    for (int co = 0; co < 32; ++co) {
#pragma unroll
      for (int k = 0; k < 5; ++k) {
        float wv = w[(co * 16 + ci) * 5 + k];
        acc0[co] += xv[k] * wv;
        acc1[co] += xv[k + 1] * wv;
      }
    }
  }
  half8 hres[4];
#pragma unroll
  for (int co = 0; co < 32; ++co) {
    float v = fmaxf(acc0[co], acc1[co]) + bias[co];
    hres[co >> 3][co & 7] = (__fp16)fmaxf(v, 0.f);
  }
  half8* frow = (half8*)(fs + tp * 40);
#pragma unroll
  for (int j = 0; j < 4; ++j) frow[j] = hres[j];
  __syncthreads();
  int lane = threadIdx.x & 63;
  int m = lane & 15;
  int q = lane >> 4;
  int wib = threadIdx.x >> 6;
  half8 bf[4];
#pragma unroll
  for (int t = 0; t < 4; ++t)
#pragma unroll
    for (int j = 0; j < 8; ++j)
      bf[t][j] = (__fp16)W1[(q * 8 + j) * 64 + t * 16 + m];
  int gnode0 = b * T2 + tp0;
#pragma unroll
  for (int tt = 0; tt < 4; ++tt) {
    int lbase = (wib * 4 + tt) * 16;
    half8 a = *(const half8*)(fs + (lbase + m) * 40 + q * 8);
    float d[4];
#pragma unroll
    for (int r = 0; r < 4; ++r) d[r] = dis[gnode0 + lbase + q * 4 + r];
#pragma unroll
    for (int t = 0; t < 4; ++t) {
      floatx4 acc = {0.f, 0.f, 0.f, 0.f};
      acc = __builtin_amdgcn_mfma_f32_16x16x32_f16(a, bf[t], acc, 0, 0, 0);
#pragma unroll
      for (int r = 0; r < 4; ++r)
        xw[(size_t)(gnode0 + lbase + q * 4 + r) * 64 + t * 16 + m] = (__fp16)(acc[r] * d[r]);
    }
  }
}

// ---------------- pass C: partition edges (packed 4B records) into bucket regions
__global__ __launch_bounds__(256) void partition_pairs(const int* __restrict__ ei, int E,
    int* __restrict__ rcnt, int* __restrict__ gpairs) {
  __shared__ int lcnt[NCB];
  __shared__ int lpk[NCB * PC_CAP];
  if (threadIdx.x < NCB) lcnt[threadIdx.x] = 0;
  __syncthreads();
  int e0 = blockIdx.x * PC_EDGES;
#pragma unroll
  for (int j = 0; j < PC_EDGES / 256; ++j) {
    int e = e0 + j * 256 + threadIdx.x;
    if (e < E) {
      int r = ei[e];
      int c = ei[E + e];
      int cb = c >> CB_SHIFT;
      int pk = r | ((c & (CB_TGT - 1)) << 17);
      int slot = atomicAdd(&lcnt[cb], 1);
      if (slot < PC_CAP) {
        lpk[cb * PC_CAP + slot] = pk;
      } else {
        int pos = atomicAdd(&rcnt[cb], 1);
        if (pos < RCAP) gpairs[(size_t)cb * RCAP + pos] = pk;
      }
    }
  }
  __syncthreads();
  int t = threadIdx.x;
  if (t < NCB) {
    int n = lcnt[t];
    if (n > PC_CAP) n = PC_CAP;
    if (n > 0) {
      int base = atomicAdd(&rcnt[t], n);
      int* dst = gpairs + (size_t)t * RCAP;
      for (int k = 0; k < n; ++k) {
        int p = base + k;
        if (p < RCAP) dst[p] = lpk[t * PC_CAP + k];
      }
    }
  }
}

// ---------------- pass D: per coarse bucket, exact-degree CSR via wave-scans
__global__ __launch_bounds__(512) void build_csr(const int* __restrict__ gpairs,
    const int* __restrict__ rcnt, int* __restrict__ ebuf,
    int* __restrict__ estart, int* __restrict__ ecnt, float* __restrict__ dis) {
  __shared__ int deg[CB_TGT];
  __shared__ int cur[CB_TGT];
  __shared__ int sc[CB_TGT];
  __shared__ int wsum[8];
  int b = blockIdx.x;
  int t = threadIdx.x;
  deg[t] = 0;
  cur[t] = 0;
  __syncthreads();
  int m = rcnt[b];
  if (m > RCAP) m = RCAP;
  const int* reg = gpairs + (size_t)b * RCAP;
  for (int k = t; k < m; k += 512)
    atomicAdd(&deg[(reg[k] >> 17) & (CB_TGT - 1)], 1);
  __syncthreads();
  int d = deg[t];
  int lane = t & 63;
  int wv = t >> 6;
  int sum = d;
#pragma unroll
  for (int off = 1; off < 64; off <<= 1) {
    int v = __shfl_up(sum, off, 64);
    if (lane >= off) sum += v;
  }
  if (lane == 63) wsum[wv] = sum;
  __syncthreads();
  int prefix = 0;
#pragma unroll
  for (int i = 0; i < 8; ++i) prefix += (i < wv) ? wsum[i] : 0;
  int excl = prefix + sum - d;
  int gi = (b << CB_SHIFT) + t;
  int base = b * RCAP;
  estart[gi] = base + excl;
  ecnt[gi] = d;
  dis[gi] = rsqrtf((float)d + 1.0f);
  sc[t] = excl;
  __syncthreads();
  for (int k = t; k < m; k += 512) {
    int p = reg[k];
    int lc = (p >> 17) & (CB_TGT - 1);
    int off = atomicAdd(&cur[lc], 1);
    ebuf[base + sc[lc] + off] = p & PK_RMASK;
  }
}

// ======== dual-node gather: 8 edge-slots x 8 lanes, 16B rows, zero-row tails.
// Per iteration: 8 half8 loads in flight (4 per node, 8 rows each = 64 edges).
#define GATHER2(cA_, stA_, cB_, stB_, A, B)                                   \
  {                                                                           \
    int nmax = (cA_ > cB_) ? cA_ : cB_;                                       \
    int niter = (nmax + 31) >> 5;                                             \
    for (int it = 0; it < niter; ++it) {                                      \
      int s0 = it << 5;                                                       \
      half8 hA[4], hB[4];                                                     \
      _Pragma("unroll")                                                       \
      for (int j = 0; j < 4; ++j) {                                           \
        int k = s0 + j * 8 + es;                                              \
        int rA = (k < cA_) ? (sidx[stA_ + k] & PK_RMASK) : ZROW;              \
        int rB = (k < cB_) ? (sidx[stB_ + k] & PK_RMASK) : ZROW;              \
        hA[j] = *(const half8*)(tab + (size_t)rA * 64 + ch * 8);              \
        hB[j] = *(const half8*)(tab + (size_t)rB * 64 + ch * 8);              \
      }                                                                       \
      _Pragma("unroll")                                                       \
      for (int j = 0; j < 4; ++j) {                                           \
        _Pragma("unroll")                                                     \
        for (int f = 0; f < 8; ++f) {                                         \
          A[f] += (float)hA[j][f];                                            \
          B[f] += (float)hB[j][f];                                            \
        }                                                                     \
      }                                                                       \
    }                                                                         \
  }

#define REDUCE8(A)                                                            \
  _Pragma("unroll")                                                           \
  for (int f = 0; f < 8; ++f) {                                               \
    A[f] += __shfl_xor(A[f], 8, 64);                                          \
    A[f] += __shfl_xor(A[f], 16, 64);                                         \
    A[f] += __shfl_xor(A[f], 32, 64);                                         \
  }

// ---------------- agg1 + gemm2 fused (fp16 tables, staged span, dual-node)
__global__ __launch_bounds__(256) void agg1_gemm2(const __fp16* __restrict__ tab,
    const int* __restrict__ ebuf, const int* __restrict__ estart,
    const int* __restrict__ ecnt, const float* __restrict__ dis,
    const float* __restrict__ bias, const float* __restrict__ W2,
    __fp16* __restrict__ xw2, int N) {
  __shared__ __fp16 g1s[16 * 72];
  __shared__ int sidx[EC];
  __shared__ int sst[16], scn[16];
  int t = threadIdx.x;
  int base16 = blockIdx.x * 16;
  if (t < 16) {
    sst[t] = estart[base16 + t];
    scn[t] = ecnt[base16 + t];
  }
  __syncthreads();
  int span0 = sst[0];
  int total = sst[15] + scn[15] - span0;
  if (total > EC) total = EC;
  for (int k = t; k < total; k += 256) sidx[k] = ebuf[span0 + k];
  __syncthreads();
  int lane = t & 63;
  int es = lane >> 3;
  int ch = lane & 7;
  int wib = t >> 6;
  float bv[8];
#pragma unroll
  for (int j = 0; j < 8; ++j) bv[j] = bias[ch * 8 + j];
  for (int jj = 0; jj < 4; jj += 2) {
    int ilA = wib * 4 + jj, ilB = ilA + 1;
    int iA = base16 + ilA, iB = base16 + ilB;
    int stA = sst[ilA] - span0, stB = sst[ilB] - span0;
    int cA = scn[ilA], cB = scn[ilB];
    if (stA + cA > EC) cA = (EC > stA) ? (EC - stA) : 0;
    if (stB + cB > EC) cB = (EC > stB) ? (EC - stB) : 0;
    float A[8], B[8];
#pragma unroll
    for (int f = 0; f < 8; ++f) { A[f] = 0.f; B[f] = 0.f; }
    GATHER2(cA, stA, cB, stB, A, B)
    REDUCE8(A)
    REDUCE8(B)
    if (es == 0) {
      float diA = dis[iA], diB = dis[iB];
      half8 hsA = *(const half8*)(tab + (size_t)iA * 64 + ch * 8);
      half8 hsB = *(const half8*)(tab + (size_t)iB * 64 + ch * 8);
      half8 rA, rB;
#pragma unroll
      for (int f = 0; f < 8; ++f) {
        rA[f] = (__fp16)fmaxf((A[f] + (float)hsA[f]) * diA + bv[f], 0.f);
        rB[f] = (__fp16)fmaxf((B[f] + (float)hsB[f]) * diB + bv[f], 0.f);
      }
      *(half8*)(g1s + ilA * 72 + ch * 8) = rA;
      *(half8*)(g1s + ilB * 72 + ch * 8) = rB;
    }
  }
  __syncthreads();
  // gemm2 epilogue: wave wib computes output columns wib*16..wib*16+15
  int m = lane & 15;
  int q = lane >> 4;
  half8 b0, b1;
#pragma unroll
  for (int j = 0; j < 8; ++j) {
    b0[j] = (__fp16)W2[(q * 8 + j) * 64 + wib * 16 + m];
    b1[j] = (__fp16)W2[(32 + q * 8 + j) * 64 + wib * 16 + m];
  }
  half8 a0 = *(const half8*)(g1s + m * 72 + q * 8);
  half8 a1 = *(const half8*)(g1s + m * 72 + 32 + q * 8);
  floatx4 acc = {0.f, 0.f, 0.f, 0.f};
  acc = __builtin_amdgcn_mfma_f32_16x16x32_f16(a0, b0, acc, 0, 0, 0);
  acc = __builtin_amdgcn_mfma_f32_16x16x32_f16(a1, b1, acc, 0, 0, 0);
#pragma unroll
  for (int r = 0; r < 4; ++r) {
    int node = base16 + q * 4 + r;
    xw2[(size_t)node * 64 + wib * 16 + m] = (__fp16)(acc[r] * dis[node]);
  }
}

// ---------------- GCN aggregate layer-2 (staged span, dual-node) + mean-pool
__global__ __launch_bounds__(256) void gcn_aggregate_pool(const __fp16* __restrict__ tab,
    const int* __restrict__ ebuf, const int* __restrict__ estart,
    const int* __restrict__ ecnt, const float* __restrict__ dis,
    const float* __restrict__ bias, float* __restrict__ pool, int N) {
  __shared__ float red[4][64];
  __shared__ int sidx[EC];
  __shared__ int sst[16], scn[16];
  int t = threadIdx.x;
  int base16 = blockIdx.x * 16;
  if (t < 16) {
    sst[t] = estart[base16 + t];
    scn[t] = ecnt[base16 + t];
  }
  __syncthreads();
  int span0 = sst[0];
  int total = sst[15] + scn[15] - span0;
  if (total > EC) total = EC;
  for (int k = t; k < total; k += 256) sidx[k] = ebuf[span0 + k];
  __syncthreads();
  int lane = t & 63;
  int es = lane >> 3;
  int ch = lane & 7;
  int wib = t >> 6;
  float bv[8];
#pragma unroll
  for (int j = 0; j < 8; ++j) bv[j] = bias[ch * 8 + j];
  float ps[8];
#pragma unroll
  for (int f = 0; f < 8; ++f) ps[f] = 0.f;
  for (int jj = 0; jj < 4; jj += 2) {
    int ilA = wib * 4 + jj, ilB = ilA + 1;
    int iA = base16 + ilA, iB = base16 + ilB;
    int stA = sst[ilA] - span0, stB = sst[ilB] - span0;
    int cA = scn[ilA], cB = scn[ilB];
    if (stA + cA > EC) cA = (EC > stA) ? (EC - stA) : 0;
    if (stB + cB > EC) cB = (EC > stB) ? (EC - stB) : 0;
    float A[8], B[8];
#pragma unroll
    for (int f = 0; f < 8; ++f) { A[f] = 0.f; B[f] = 0.f; }
    GATHER2(cA, stA, cB, stB, A, B)
    REDUCE8(A)
    REDUCE8(B)
    if (es == 0) {
      float diA = dis[iA], diB = dis[iB];
      half8 hsA = *(const half8*)(tab + (size_t)iA * 64 + ch * 8);
      half8 hsB = *(const half8*)(tab + (size_t)iB * 64 + ch * 8);
#pragma unroll
      for (int f = 0; f < 8; ++f) {
        ps[f] += fmaxf((A[f] + (float)hsA[f]) * diA + bv[f], 0.f);
        ps[f] += fmaxf((B[f] + (float)hsB[f]) * diB + bv[f], 0.f);
      }
    }
  }
  if (es == 0) {
#pragma unroll
    for (int f = 0; f < 8; ++f) red[wib][ch * 8 + f] = ps[f];
  }
  __syncthreads();
  if (threadIdx.x < 64) {
    int f = threadIdx.x;
    float sum = red[0][f] + red[1][f] + red[2][f] + red[3][f];
    int b = (blockIdx.x * 16) >> 11;
    atomicAdd(&pool[b * 64 + f], sum);
  }
}

// ---------------- classifier: out[b] = (pool[b]/2048) @ cls_w + cls_b
__global__ __launch_bounds__(64) void classify(const float* __restrict__ pool,
    const float* __restrict__ cw, const float* __restrict__ cb,
    float* __restrict__ out) {
  __shared__ float pl[64];
  int b = blockIdx.x;
  int t = threadIdx.x;
  pl[t] = pool[b * 64 + t] * (1.0f / (float)T2);
  __syncthreads();
  if (t < NOUT) {
    float a = cb[t];
#pragma unroll
    for (int k = 0; k < 64; ++k) a += pl[k] * cw[k * NOUT + t];
    out[b * NOUT + t] = a;
  }
}

extern "C" void kernel_launch(void* const* d_in, const int* in_sizes, int n_in,
                              void* d_out, int out_size, void* d_ws, size_t ws_size,
                              hipStream_t stream) {
  const float* x    = (const float*)d_in[0];
  const int*   ei   = (const int*)d_in[1];
  const float* c1w  = (const float*)d_in[2];
  const float* c1b  = (const float*)d_in[3];
  const float* c2w  = (const float*)d_in[4];
  const float* c2b  = (const float*)d_in[5];
  const float* g1w  = (const float*)d_in[6];
  const float* g1b  = (const float*)d_in[7];
  const float* g2w  = (const float*)d_in[8];
  const float* g2b  = (const float*)d_in[9];
  const float* cw   = (const float*)d_in[10];
  const float* cb   = (const float*)d_in[11];
  float* out = (float*)d_out;
  int E = in_sizes[1] / 2;
  const int N = N_NODES;

  // workspace layout (bytes); xw/xw2 have N+1 rows (last = zero row)
  char* ws = (char*)d_ws;
  int*    gpairs = (int*)(ws);                     //  9,437,184 (packed 4B)
  int*    ebuf   = (int*)(ws + 9437184);           //  9,437,184
  int*    rcnt   = (int*)(ws + 18874368);          //      4,096
  int*    estart = (int*)(ws + 18878464);          //    524,288
  int*    ecnt   = (int*)(ws + 19402752);          //    524,288
  float*  dis    = (float*)(ws + 19927040);        //    524,288
  float*  pool   = (float*)(ws + 20451328);        //     16,384
  __fp16* xw     = (__fp16*)(ws + 20467712);       // 16,777,472 (N+1 rows fp16)
  __fp16* xw2    = (__fp16*)(ws + 37245184);       // 16,777,472
  __fp16* h1     = (__fp16*)(ws + 54022656);       //  8,388,608

  hipMemsetAsync(rcnt, 0, NCB * sizeof(int), stream);
  hipMemsetAsync(pool, 0, BATCH * HID * sizeof(float), stream);
  hipMemsetAsync(xw + (size_t)N * 64, 0, 128, stream);   // zero row
  hipMemsetAsync(xw2 + (size_t)N * 64, 0, 128, stream);  // zero row

  conv1_kernel<<<dim3(BATCH * 16), dim3(256), 0, stream>>>(x, c1w, c1b, h1);
  partition_pairs<<<dim3((E + PC_EDGES - 1) / PC_EDGES), dim3(256), 0, stream>>>(ei, E, rcnt, gpairs);
  build_csr<<<dim3(NCB), dim3(512), 0, stream>>>(gpairs, rcnt, ebuf, estart, ecnt, dis);

  conv2_gemm1<<<dim3(BATCH * 8), dim3(256), 0, stream>>>(h1, c2w, c2b, g1w, dis, xw);
  agg1_gemm2<<<dim3(N / 16), dim3(256), 0, stream>>>(xw, ebuf, estart, ecnt, dis, g1b, g2w, xw2, N);
  gcn_aggregate_pool<<<dim3(N / 16), dim3(256), 0, stream>>>(xw2, ebuf, estart, ecnt, dis, g2b, pool, N);

  classify<<<dim3(BATCH), dim3(64), 0, stream>>>(pool, cw, cb, out);
}

// Round 15
// 337.821 us; speedup vs baseline: 1.0659x; 1.0659x over previous
//
#include <hip/hip_runtime.h>
#include <hip/hip_bf16.h>
#include <hip/hip_fp16.h>

// Problem constants
#define BATCH 64
#define C_IN 16
#define T0 8192
#define T1 4096   // after pool1
#define T2 2048   // after pool2 (nodes per batch)
#define N_NODES (BATCH * T2)   // 131072
#define HID 64
#define NOUT 10

// Coarse-bucket edge partition parameters
#define NCB 256
#define CB_SHIFT 9
#define CB_TGT 512
#define RCAP 9216
#define PC_EDGES 2048
#define PC_CAP 28

// packed edge record: bits[0:17) = source r, bits[17:26) = local col
#define PK_RMASK 0x1FFFF

// per-block staged edge-span capacity
#define EC 1024

// zero-row index (tables have N_NODES+1 rows; row N_NODES is all zeros)
#define ZROW N_NODES

typedef __fp16 half8 __attribute__((ext_vector_type(8)));
typedef __fp16 half4v __attribute__((ext_vector_type(4)));
typedef float floatx4 __attribute__((ext_vector_type(4)));

// ---------------- conv1: [64,16,8192] -> relu -> pool2 -> h1 fp16 [64,16,4096]
__global__ __launch_bounds__(256) void conv1_kernel(const float* __restrict__ x,
    const float* __restrict__ w, const float* __restrict__ bias,
    __fp16* __restrict__ h1) {
  __shared__ float xs[16 * 520];
  int b = blockIdx.x >> 4;
  int tp0 = (blockIdx.x & 15) * 256;
  int t_base = tp0 * 2 - 2;
  const float* xb = x + (size_t)b * C_IN * T0;
  for (int idx = threadIdx.x; idx < 16 * 516; idx += 256) {
    int ci = idx / 516;
    int off = idx - ci * 516;
    int gt = t_base + off;
    float v = 0.f;
    if (gt >= 0 && gt < T0) v = xb[ci * T0 + gt];
    xs[ci * 520 + off] = v;
  }
  __syncthreads();
  int tp = threadIdx.x;
  float acc0[16], acc1[16];
#pragma unroll
  for (int co = 0; co < 16; ++co) { acc0[co] = 0.f; acc1[co] = 0.f; }
#pragma unroll 4
  for (int ci = 0; ci < 16; ++ci) {
    float xv[6];
#pragma unroll
    for (int k = 0; k < 6; ++k) xv[k] = xs[ci * 520 + 2 * tp + k];
#pragma unroll
    for (int co = 0; co < 16; ++co) {
#pragma unroll
      for (int k = 0; k < 5; ++k) {
        float wv = w[(co * 16 + ci) * 5 + k];
        acc0[co] += xv[k] * wv;
        acc1[co] += xv[k + 1] * wv;
      }
    }
  }
#pragma unroll
  for (int co = 0; co < 16; ++co) {
    float v = fmaxf(acc0[co], acc1[co]) + bias[co];
    v = fmaxf(v, 0.f);
    h1[((size_t)b * 16 + co) * T1 + tp0 + tp] = (__fp16)v;
  }
}

// ---------------- conv2 + gemm1 fused: h1 -> relu/pool -> (LDS) -> MFMA @W1
__global__ __launch_bounds__(256) void conv2_gemm1(const __fp16* __restrict__ h1,
    const float* __restrict__ w, const float* __restrict__ bias,
    const float* __restrict__ W1, const float* __restrict__ dis,
    __fp16* __restrict__ xw) {
  __shared__ float xs[16 * 520];
  __shared__ __fp16 fs[256 * 40];
  int b = blockIdx.x >> 3;
  int tp0 = (blockIdx.x & 7) * 256;
  int t_base = tp0 * 2 - 2;
  const __fp16* xb = h1 + (size_t)b * 16 * T1;
  for (int idx = threadIdx.x; idx < 16 * 516; idx += 256) {
    int ci = idx / 516;
    int off = idx - ci * 516;
    int gt = t_base + off;
    float v = 0.f;
    if (gt >= 0 && gt < T1) v = (float)xb[ci * T1 + gt];
    xs[ci * 520 + off] = v;
  }
  __syncthreads();
  int tp = threadIdx.x;
  float acc0[32], acc1[32];
#pragma unroll
  for (int co = 0; co < 32; ++co) { acc0[co] = 0.f; acc1[co] = 0.f; }
#pragma unroll 2
  for (int ci = 0; ci < 16; ++ci) {
    float xv[6];
#pragma unroll
    for (int k = 0; k < 6; ++k) xv[k] = xs[ci * 520 + 2 * tp + k];
#pragma unroll
    for (int co = 0; co < 32; ++co) {
#pragma unroll
      for (int k = 0; k < 5; ++k) {
        float wv = w[(co * 16 + ci) * 5 + k];
        acc0[co] += xv[k] * wv;
        acc1[co] += xv[k + 1] * wv;
      }
    }
  }
  half8 hres[4];
#pragma unroll
  for (int co = 0; co < 32; ++co) {
    float v = fmaxf(acc0[co], acc1[co]) + bias[co];
    hres[co >> 3][co & 7] = (__fp16)fmaxf(v, 0.f);
  }
  half8* frow = (half8*)(fs + tp * 40);
#pragma unroll
  for (int j = 0; j < 4; ++j) frow[j] = hres[j];
  __syncthreads();
  int lane = threadIdx.x & 63;
  int m = lane & 15;
  int q = lane >> 4;
  int wib = threadIdx.x >> 6;
  half8 bf[4];
#pragma unroll
  for (int t = 0; t < 4; ++t)
#pragma unroll
    for (int j = 0; j < 8; ++j)
      bf[t][j] = (__fp16)W1[(q * 8 + j) * 64 + t * 16 + m];
  int gnode0 = b * T2 + tp0;
#pragma unroll
  for (int tt = 0; tt < 4; ++tt) {
    int lbase = (wib * 4 + tt) * 16;
    half8 a = *(const half8*)(fs + (lbase + m) * 40 + q * 8);
    float d[4];
#pragma unroll
    for (int r = 0; r < 4; ++r) d[r] = dis[gnode0 + lbase + q * 4 + r];
#pragma unroll
    for (int t = 0; t < 4; ++t) {
      floatx4 acc = {0.f, 0.f, 0.f, 0.f};
      acc = __builtin_amdgcn_mfma_f32_16x16x32_f16(a, bf[t], acc, 0, 0, 0);
#pragma unroll
      for (int r = 0; r < 4; ++r)
        xw[(size_t)(gnode0 + lbase + q * 4 + r) * 64 + t * 16 + m] = (__fp16)(acc[r] * d[r]);
    }
  }
}

// ---------------- pass C: partition edges (packed 4B records) into bucket regions
__global__ __launch_bounds__(256) void partition_pairs(const int* __restrict__ ei, int E,
    int* __restrict__ rcnt, int* __restrict__ gpairs) {
  __shared__ int lcnt[NCB];
  __shared__ int lpk[NCB * PC_CAP];
  if (threadIdx.x < NCB) lcnt[threadIdx.x] = 0;
  __syncthreads();
  int e0 = blockIdx.x * PC_EDGES;
#pragma unroll
  for (int j = 0; j < PC_EDGES / 256; ++j) {
    int e = e0 + j * 256 + threadIdx.x;
    if (e < E) {
      int r = ei[e];
      int c = ei[E + e];
      int cb = c >> CB_SHIFT;
      int pk = r | ((c & (CB_TGT - 1)) << 17);
      int slot = atomicAdd(&lcnt[cb], 1);
      if (slot < PC_CAP) {
        lpk[cb * PC_CAP + slot] = pk;
      } else {
        int pos = atomicAdd(&rcnt[cb], 1);
        if (pos < RCAP) gpairs[(size_t)cb * RCAP + pos] = pk;
      }
    }
  }
  __syncthreads();
  int t = threadIdx.x;
  if (t < NCB) {
    int n = lcnt[t];
    if (n > PC_CAP) n = PC_CAP;
    if (n > 0) {
      int base = atomicAdd(&rcnt[t], n);
      int* dst = gpairs + (size_t)t * RCAP;
      for (int k = 0; k < n; ++k) {
        int p = base + k;
        if (p < RCAP) dst[p] = lpk[t * PC_CAP + k];
      }
    }
  }
}

// ---------------- pass D: per coarse bucket, exact-degree CSR via wave-scans
__global__ __launch_bounds__(512) void build_csr(const int* __restrict__ gpairs,
    const int* __restrict__ rcnt, int* __restrict__ ebuf,
    int* __restrict__ estart, int* __restrict__ ecnt, float* __restrict__ dis) {
  __shared__ int deg[CB_TGT];
  __shared__ int cur[CB_TGT];
  __shared__ int sc[CB_TGT];
  __shared__ int wsum[8];
  int b = blockIdx.x;
  int t = threadIdx.x;
  deg[t] = 0;
  cur[t] = 0;
  __syncthreads();
  int m = rcnt[b];
  if (m > RCAP) m = RCAP;
  const int* reg = gpairs + (size_t)b * RCAP;
  for (int k = t; k < m; k += 512)
    atomicAdd(&deg[(reg[k] >> 17) & (CB_TGT - 1)], 1);
  __syncthreads();
  int d = deg[t];
  int lane = t & 63;
  int wv = t >> 6;
  int sum = d;
#pragma unroll
  for (int off = 1; off < 64; off <<= 1) {
    int v = __shfl_up(sum, off, 64);
    if (lane >= off) sum += v;
  }
  if (lane == 63) wsum[wv] = sum;
  __syncthreads();
  int prefix = 0;
#pragma unroll
  for (int i = 0; i < 8; ++i) prefix += (i < wv) ? wsum[i] : 0;
  int excl = prefix + sum - d;
  int gi = (b << CB_SHIFT) + t;
  int base = b * RCAP;
  estart[gi] = base + excl;
  ecnt[gi] = d;
  dis[gi] = rsqrtf((float)d + 1.0f);
  sc[t] = excl;
  __syncthreads();
  for (int k = t; k < m; k += 512) {
    int p = reg[k];
    int lc = (p >> 17) & (CB_TGT - 1);
    int off = atomicAdd(&cur[lc], 1);
    ebuf[base + sc[lc] + off] = p & PK_RMASK;
  }
}

// ======== gather macro: staged edge span + 32-edge window, zero-row tails.
// wave layout: es = lane>>4 (4 edge slots), ch = lane&15 (4 feats each).
// Tail slots redirect to the all-zero row -> unconditional adds, no masks.
#define GATHER_NODE(c_, stl_, AX, AY, AZ, AW)                                   \
  {                                                                             \
    int niter = (c_ + 31) >> 5;                                                 \
    for (int it = 0; it < niter; ++it) {                                        \
      int s0 = (it << 5);                                                       \
      half4v h[8];                                                              \
      _Pragma("unroll")                                                         \
      for (int j = 0; j < 8; ++j) {                                             \
        int k = s0 + j * 4 + es;                                                \
        int r = (k < c_) ? (sidx[stl_ + k] & PK_RMASK) : ZROW;                  \
        h[j] = *(const half4v*)(tab + (size_t)r * 64 + ch * 4);                 \
      }                                                                         \
      _Pragma("unroll")                                                         \
      for (int j = 0; j < 8; ++j) {                                             \
        AX += (float)h[j][0];                                                   \
        AY += (float)h[j][1];                                                   \
        AZ += (float)h[j][2];                                                   \
        AW += (float)h[j][3];                                                   \
      }                                                                         \
    }                                                                           \
  }

// ---------------- agg1 + gemm2 fused (fp16 tables, staged edge span)
__global__ __launch_bounds__(256) void agg1_gemm2(const __fp16* __restrict__ tab,
    const int* __restrict__ ebuf, const int* __restrict__ estart,
    const int* __restrict__ ecnt, const float* __restrict__ dis,
    const float* __restrict__ bias, const float* __restrict__ W2,
    __fp16* __restrict__ xw2, int N) {
  __shared__ __fp16 g1s[16 * 72];
  __shared__ int sidx[EC];
  __shared__ int sst[16], scn[16];
  int t = threadIdx.x;
  int base16 = blockIdx.x * 16;
  if (t < 16) {
    sst[t] = estart[base16 + t];
    scn[t] = ecnt[base16 + t];
  }
  __syncthreads();
  int span0 = sst[0];
  int total = sst[15] + scn[15] - span0;
  if (total > EC) total = EC;
  for (int k = t; k < total; k += 256) sidx[k] = ebuf[span0 + k];
  __syncthreads();
  int lane = t & 63;
  int es = lane >> 4;
  int ch = lane & 15;
  int wib = t >> 6;
  float4 bv = *(const float4*)(bias + ch * 4);
#pragma unroll
  for (int jj = 0; jj < 4; ++jj) {
    int il = wib * 4 + jj;
    int i = base16 + il;
    int stl = sst[il] - span0;
    int c = scn[il];
    if (stl + c > EC) c = (EC > stl) ? (EC - stl) : 0;
    float di = dis[i];
    float ax = 0.f, ay = 0.f, az = 0.f, aw = 0.f;
    GATHER_NODE(c, stl, ax, ay, az, aw)
    ax += __shfl_xor(ax, 16, 64); ax += __shfl_xor(ax, 32, 64);
    ay += __shfl_xor(ay, 16, 64); ay += __shfl_xor(ay, 32, 64);
    az += __shfl_xor(az, 16, 64); az += __shfl_xor(az, 32, 64);
    aw += __shfl_xor(aw, 16, 64); aw += __shfl_xor(aw, 32, 64);
    half4v hs = *(const half4v*)(tab + (size_t)i * 64 + ch * 4);
    if (es == 0) {
      half4v r;
      r[0] = (__fp16)fmaxf((ax + (float)hs[0]) * di + bv.x, 0.f);
      r[1] = (__fp16)fmaxf((ay + (float)hs[1]) * di + bv.y, 0.f);
      r[2] = (__fp16)fmaxf((az + (float)hs[2]) * di + bv.z, 0.f);
      r[3] = (__fp16)fmaxf((aw + (float)hs[3]) * di + bv.w, 0.f);
      *(half4v*)(g1s + il * 72 + ch * 4) = r;
    }
  }
  __syncthreads();
  // gemm2 epilogue: wave wib computes output columns wib*16..wib*16+15
  int m = lane & 15;
  int q = lane >> 4;
  half8 b0, b1;
#pragma unroll
  for (int j = 0; j < 8; ++j) {
    b0[j] = (__fp16)W2[(q * 8 + j) * 64 + wib * 16 + m];
    b1[j] = (__fp16)W2[(32 + q * 8 + j) * 64 + wib * 16 + m];
  }
  half8 a0 = *(const half8*)(g1s + m * 72 + q * 8);
  half8 a1 = *(const half8*)(g1s + m * 72 + 32 + q * 8);
  floatx4 acc = {0.f, 0.f, 0.f, 0.f};
  acc = __builtin_amdgcn_mfma_f32_16x16x32_f16(a0, b0, acc, 0, 0, 0);
  acc = __builtin_amdgcn_mfma_f32_16x16x32_f16(a1, b1, acc, 0, 0, 0);
#pragma unroll
  for (int r = 0; r < 4; ++r) {
    int node = base16 + q * 4 + r;
    xw2[(size_t)node * 64 + wib * 16 + m] = (__fp16)(acc[r] * dis[node]);
  }
}

// ---------------- GCN aggregate layer-2 (fp16 table, staged span) + mean-pool
__global__ __launch_bounds__(256) void gcn_aggregate_pool(const __fp16* __restrict__ tab,
    const int* __restrict__ ebuf, const int* __restrict__ estart,
    const int* __restrict__ ecnt, const float* __restrict__ dis,
    const float* __restrict__ bias, float* __restrict__ pool, int N) {
  __shared__ float4 red[4][16];
  __shared__ int sidx[EC];
  __shared__ int sst[16], scn[16];
  int t = threadIdx.x;
  int base16 = blockIdx.x * 16;
  if (t < 16) {
    sst[t] = estart[base16 + t];
    scn[t] = ecnt[base16 + t];
  }
  __syncthreads();
  int span0 = sst[0];
  int total = sst[15] + scn[15] - span0;
  if (total > EC) total = EC;
  for (int k = t; k < total; k += 256) sidx[k] = ebuf[span0 + k];
  __syncthreads();
  int lane = t & 63;
  int es = lane >> 4;
  int ch = lane & 15;
  int wib = t >> 6;
  float4 bv = *(const float4*)(bias + ch * 4);
  float px = 0.f, py = 0.f, pz = 0.f, pw = 0.f;
#pragma unroll
  for (int jj = 0; jj < 4; ++jj) {
    int il = wib * 4 + jj;
    int i = base16 + il;
    int stl = sst[il] - span0;
    int c = scn[il];
    if (stl + c > EC) c = (EC > stl) ? (EC - stl) : 0;
    float di = dis[i];
    float ax = 0.f, ay = 0.f, az = 0.f, aw = 0.f;
    GATHER_NODE(c, stl, ax, ay, az, aw)
    ax += __shfl_xor(ax, 16, 64); ax += __shfl_xor(ax, 32, 64);
    ay += __shfl_xor(ay, 16, 64); ay += __shfl_xor(ay, 32, 64);
    az += __shfl_xor(az, 16, 64); az += __shfl_xor(az, 32, 64);
    aw += __shfl_xor(aw, 16, 64); aw += __shfl_xor(aw, 32, 64);
    half4v hs = *(const half4v*)(tab + (size_t)i * 64 + ch * 4);
    px += fmaxf((ax + (float)hs[0]) * di + bv.x, 0.f);
    py += fmaxf((ay + (float)hs[1]) * di + bv.y, 0.f);
    pz += fmaxf((az + (float)hs[2]) * di + bv.z, 0.f);
    pw += fmaxf((aw + (float)hs[3]) * di + bv.w, 0.f);
  }
  if (es == 0) red[wib][ch] = make_float4(px, py, pz, pw);
  __syncthreads();
  if (threadIdx.x < 64) {
    int f = threadIdx.x;
    int c4 = f >> 2, j4 = f & 3;
    const float* r0 = (const float*)&red[0][c4];
    const float* r1 = (const float*)&red[1][c4];
    const float* r2 = (const float*)&red[2][c4];
    const float* r3 = (const float*)&red[3][c4];
    float sum = r0[j4] + r1[j4] + r2[j4] + r3[j4];
    int b = (blockIdx.x * 16) >> 11;
    atomicAdd(&pool[b * 64 + f], sum);
  }
}

// ---------------- classifier: out[b] = (pool[b]/2048) @ cls_w + cls_b
__global__ __launch_bounds__(64) void classify(const float* __restrict__ pool,
    const float* __restrict__ cw, const float* __restrict__ cb,
    float* __restrict__ out) {
  __shared__ float pl[64];
  int b = blockIdx.x;
  int t = threadIdx.x;
  pl[t] = pool[b * 64 + t] * (1.0f / (float)T2);
  __syncthreads();
  if (t < NOUT) {
    float a = cb[t];
#pragma unroll
    for (int k = 0; k < 64; ++k) a += pl[k] * cw[k * NOUT + t];
    out[b * NOUT + t] = a;
  }
}

extern "C" void kernel_launch(void* const* d_in, const int* in_sizes, int n_in,
                              void* d_out, int out_size, void* d_ws, size_t ws_size,
                              hipStream_t stream) {
  const float* x    = (const float*)d_in[0];
  const int*   ei   = (const int*)d_in[1];
  const float* c1w  = (const float*)d_in[2];
  const float* c1b  = (const float*)d_in[3];
  const float* c2w  = (const float*)d_in[4];
  const float* c2b  = (const float*)d_in[5];
  const float* g1w  = (const float*)d_in[6];
  const float* g1b  = (const float*)d_in[7];
  const float* g2w  = (const float*)d_in[8];
  const float* g2b  = (const float*)d_in[9];
  const float* cw   = (const float*)d_in[10];
  const float* cb   = (const float*)d_in[11];
  float* out = (float*)d_out;
  int E = in_sizes[1] / 2;
  const int N = N_NODES;

  // workspace layout (bytes); xw/xw2 have N+1 rows (last = zero row)
  char* ws = (char*)d_ws;
  int*    gpairs = (int*)(ws);                     //  9,437,184 (packed 4B)
  int*    ebuf   = (int*)(ws + 9437184);           //  9,437,184
  int*    rcnt   = (int*)(ws + 18874368);          //      4,096
  int*    estart = (int*)(ws + 18878464);          //    524,288
  int*    ecnt   = (int*)(ws + 19402752);          //    524,288
  float*  dis    = (float*)(ws + 19927040);        //    524,288
  float*  pool   = (float*)(ws + 20451328);        //     16,384
  __fp16* xw     = (__fp16*)(ws + 20467712);       // 16,777,472 (N+1 rows fp16)
  __fp16* xw2    = (__fp16*)(ws + 37245184);       // 16,777,472
  __fp16* h1     = (__fp16*)(ws + 54022656);       //  8,388,608

  hipMemsetAsync(rcnt, 0, NCB * sizeof(int), stream);
  hipMemsetAsync(pool, 0, BATCH * HID * sizeof(float), stream);
  hipMemsetAsync(xw + (size_t)N * 64, 0, 128, stream);   // zero row
  hipMemsetAsync(xw2 + (size_t)N * 64, 0, 128, stream);  // zero row

  conv1_kernel<<<dim3(BATCH * 16), dim3(256), 0, stream>>>(x, c1w, c1b, h1);
  partition_pairs<<<dim3((E + PC_EDGES - 1) / PC_EDGES), dim3(256), 0, stream>>>(ei, E, rcnt, gpairs);
  build_csr<<<dim3(NCB), dim3(512), 0, stream>>>(gpairs, rcnt, ebuf, estart, ecnt, dis);

  conv2_gemm1<<<dim3(BATCH * 8), dim3(256), 0, stream>>>(h1, c2w, c2b, g1w, dis, xw);
  agg1_gemm2<<<dim3(N / 16), dim3(256), 0, stream>>>(xw, ebuf, estart, ecnt, dis, g1b, g2w, xw2, N);
  gcn_aggregate_pool<<<dim3(N / 16), dim3(256), 0, stream>>>(xw2, ebuf, estart, ecnt, dis, g2b, pool, N);

  classify<<<dim3(BATCH), dim3(64), 0, stream>>>(pool, cw, cb, out);
}